// Round 1
// baseline (3854.939 us; speedup 1.0000x reference)
//
#include <hip/hip_runtime.h>
#include <math.h>

#define DEV __device__ __forceinline__

typedef __attribute__((ext_vector_type(4))) float f32x4;
typedef __attribute__((ext_vector_type(8))) short bf16x8;

DEV ushort f2bf(float x) {
  unsigned u = __float_as_uint(x);
  u = (u + 0x7FFFu + ((u >> 16) & 1u)) >> 16;
  return (ushort)u;
}

DEV float gelu_exact(float x) {
  return 0.5f * x * (1.0f + erff(x * 0.70710678118654752f));
}

DEV void async16(const void* g, void* l) {
  __builtin_amdgcn_global_load_lds((const __attribute__((address_space(1))) void*)g,
                                   (__attribute__((address_space(3))) void*)l, 16, 0, 0);
}

// ---------------------------------------------------------------------------
// f32 -> bf16 elementwise convert (n divisible by 4)
// ---------------------------------------------------------------------------
__global__ void f32_to_bf16_vec(const float* __restrict__ src, ushort* __restrict__ dst, int n4) {
  int i = blockIdx.x * 256 + threadIdx.x;
  if (i < n4) {
    float4 f = ((const float4*)src)[i];
    ushort4 u;
    u.x = f2bf(f.x); u.y = f2bf(f.y); u.z = f2bf(f.z); u.w = f2bf(f.w);
    ((ushort4*)dst)[i] = u;
  }
}

// ---------------------------------------------------------------------------
// bf16 GEMM:  Y[M,N] = A[M,K] @ W[N,K]^T + bias   (m97 structure)
// EPI 0: Yf = val   1: Yf += val   2: Ybf = bf16(gelu(val))
// M%128==0, N%128==0, K%32==0
// ---------------------------------------------------------------------------
template <int EPI>
__launch_bounds__(256, 2)
__global__ void gemm_bt(const ushort* __restrict__ A, const ushort* __restrict__ W,
                        const float* __restrict__ bias, float* __restrict__ Yf,
                        ushort* __restrict__ Ybf, int M, int N, int K) {
  __shared__ ushort As[128 * 32];
  __shared__ ushort Bs[128 * 32];
  const int tid  = threadIdx.x;
  const int lane = tid & 63;
  const int wave = tid >> 6;
  const int wr = wave >> 1, wc = wave & 1;
  const int m0 = blockIdx.y * 128, n0 = blockIdx.x * 128;
  const int q = lane >> 4, ln = lane & 15;
  const int srow = lane >> 2;
  const int scol = (lane & 3) * 8;

  f32x4 acc[4][4] = {};

  const ushort* gA = A + (size_t)(m0 + wave * 32 + srow) * K + scol;
  const ushort* gB = W + (size_t)(n0 + wave * 32 + srow) * K + scol;
  ushort* lA = &As[(wave * 32) * 32];
  ushort* lB = &Bs[(wave * 32) * 32];

  for (int k0 = 0; k0 < K; k0 += 32) {
    async16(gA + k0, lA);
    async16(gA + k0 + (size_t)16 * K, lA + 16 * 32);
    async16(gB + k0, lB);
    async16(gB + k0 + (size_t)16 * K, lB + 16 * 32);
    __syncthreads();
    bf16x8 af[4], bfr[4];
#pragma unroll
    for (int t = 0; t < 4; ++t)
      af[t] = *(const bf16x8*)&As[(wr * 64 + t * 16 + ln) * 32 + q * 8];
#pragma unroll
    for (int t = 0; t < 4; ++t)
      bfr[t] = *(const bf16x8*)&Bs[(wc * 64 + t * 16 + ln) * 32 + q * 8];
#pragma unroll
    for (int mt = 0; mt < 4; ++mt)
#pragma unroll
      for (int nt = 0; nt < 4; ++nt)
        acc[mt][nt] = __builtin_amdgcn_mfma_f32_16x16x32_bf16(af[mt], bfr[nt], acc[mt][nt], 0, 0, 0);
    __syncthreads();
  }

#pragma unroll
  for (int mt = 0; mt < 4; ++mt) {
    const int gm = m0 + wr * 64 + mt * 16 + q * 4;
#pragma unroll
    for (int nt = 0; nt < 4; ++nt) {
      const int gn = n0 + wc * 64 + nt * 16 + ln;
      const float bi = bias[gn];
#pragma unroll
      for (int r = 0; r < 4; ++r) {
        const float val = acc[mt][nt][r] + bi;
        const size_t idx = (size_t)(gm + r) * N + gn;
        if (EPI == 0)      Yf[idx] = val;
        else if (EPI == 1) Yf[idx] += val;
        else               Ybf[idx] = f2bf(gelu_exact(val));
      }
    }
  }
}

// ---------------------------------------------------------------------------
// LayerNorm over D=512, one wave per row. BF=1: bf16 out, BF=0: f32 out
// ---------------------------------------------------------------------------
template <int BF>
__launch_bounds__(256)
__global__ void ln512(const float* __restrict__ X, const float* __restrict__ G,
                      const float* __restrict__ Bb, void* __restrict__ Yv, int rows) {
  const int lane = threadIdx.x & 63;
  const int wave = threadIdx.x >> 6;
  const int row = blockIdx.x * 4 + wave;
  if (row >= rows) return;
  const float* x = X + (size_t)row * 512 + lane * 8;
  float4 v0 = *(const float4*)x;
  float4 v1 = *(const float4*)(x + 4);
  float s = v0.x + v0.y + v0.z + v0.w + v1.x + v1.y + v1.z + v1.w;
#pragma unroll
  for (int off = 32; off; off >>= 1) s += __shfl_xor(s, off);
  const float mean = s * (1.f / 512.f);
  float d[8] = {v0.x - mean, v0.y - mean, v0.z - mean, v0.w - mean,
                v1.x - mean, v1.y - mean, v1.z - mean, v1.w - mean};
  float ss = d[0]*d[0] + d[1]*d[1] + d[2]*d[2] + d[3]*d[3] +
             d[4]*d[4] + d[5]*d[5] + d[6]*d[6] + d[7]*d[7];
#pragma unroll
  for (int off = 32; off; off >>= 1) ss += __shfl_xor(ss, off);
  const float rstd = rsqrtf(ss * (1.f / 512.f) + 1e-5f);
  const float* gp = G + lane * 8;
  const float* bp = Bb + lane * 8;
  float4 g0 = *(const float4*)gp, g1 = *(const float4*)(gp + 4);
  float4 b0 = *(const float4*)bp, b1 = *(const float4*)(bp + 4);
  float y[8];
  y[0] = d[0]*rstd*g0.x + b0.x; y[1] = d[1]*rstd*g0.y + b0.y;
  y[2] = d[2]*rstd*g0.z + b0.z; y[3] = d[3]*rstd*g0.w + b0.w;
  y[4] = d[4]*rstd*g1.x + b1.x; y[5] = d[5]*rstd*g1.y + b1.y;
  y[6] = d[6]*rstd*g1.z + b1.z; y[7] = d[7]*rstd*g1.w + b1.w;
  if (BF) {
    ushort* o = (ushort*)Yv + (size_t)row * 512 + lane * 8;
    ushort4 u0, u1;
    u0.x = f2bf(y[0]); u0.y = f2bf(y[1]); u0.z = f2bf(y[2]); u0.w = f2bf(y[3]);
    u1.x = f2bf(y[4]); u1.y = f2bf(y[5]); u1.z = f2bf(y[6]); u1.w = f2bf(y[7]);
    *(ushort4*)o = u0; *(ushort4*)(o + 4) = u1;
  } else {
    float* o = (float*)Yv + (size_t)row * 512 + lane * 8;
    *(float4*)o = make_float4(y[0], y[1], y[2], y[3]);
    *(float4*)(o + 4) = make_float4(y[4], y[5], y[6], y[7]);
  }
}

// ---------------------------------------------------------------------------
// In-place L2 normalize contiguous segments of 64 floats (per-head q/k)
// ---------------------------------------------------------------------------
__launch_bounds__(256)
__global__ void l2norm64(float* __restrict__ X, int nseg) {
  const int seg = blockIdx.x * 4 + (threadIdx.x >> 6);
  const int lane = threadIdx.x & 63;
  if (seg >= nseg) return;
  float v = X[(size_t)seg * 64 + lane];
  float ss = v * v;
#pragma unroll
  for (int off = 32; off; off >>= 1) ss += __shfl_xor(ss, off);
  const float n = sqrtf(ss);
  X[(size_t)seg * 64 + lane] = v / fmaxf(n, 1e-6f);
}

// ---------------------------------------------------------------------------
// Small fp32 GEMM for slot K/V projections: Y[88,512] = X[88,512]@W[512,512]^T+b
// ---------------------------------------------------------------------------
__launch_bounds__(256)
__global__ void gemm88(const float* __restrict__ X, const float* __restrict__ W,
                       const float* __restrict__ bias, float* __restrict__ Y) {
  const int m = blockIdx.x;
  const int tid = threadIdx.x;
  __shared__ float xs[512];
  xs[tid] = X[(size_t)m * 512 + tid];
  xs[tid + 256] = X[(size_t)m * 512 + tid + 256];
  __syncthreads();
#pragma unroll
  for (int rep = 0; rep < 2; ++rep) {
    const int n = tid + rep * 256;
    const float* wr = W + (size_t)n * 512;
    float acc = bias[n];
    for (int k = 0; k < 512; k += 4) {
      float4 w4 = *(const float4*)(wr + k);
      acc += xs[k] * w4.x + xs[k+1] * w4.y + xs[k+2] * w4.z + xs[k+3] * w4.w;
    }
    Y[(size_t)m * 512 + n] = acc;
  }
}

// ---------------------------------------------------------------------------
// Causal self-attention, flash-style. Q tile 32 rows, K tile 64 cols.
// q,k,v: f32 [B*S, H*64]; out: bf16 [B*S, H*64]
// grid (32 qtiles, 64 b*h), block 256 (tx=tid&15 -> 4 k-cols, ty=tid>>4 -> 2 q-rows)
// ---------------------------------------------------------------------------
__launch_bounds__(256)
__global__ void attn_self(const float* __restrict__ Q, const float* __restrict__ K,
                          const float* __restrict__ V, ushort* __restrict__ Obf) {
  const int qt = blockIdx.x;
  const int bh = blockIdx.y;
  const int b = bh >> 3, h = bh & 7;
  const int tid = threadIdx.x;
  const int tx = tid & 15, ty = tid >> 4;
  const int tx4 = tx * 4, ty2 = ty * 2;
  __shared__ float Qs[32][65];
  __shared__ float Ks[64][65];
  __shared__ float Vs[64][65];
  __shared__ float Ps[32][65];
  __shared__ float red[32][17];
  __shared__ float mrow[32], lrow[32], arow[32];
  const size_t base = ((size_t)(b * 1024)) * 512 + h * 64;

  {
    const int r = tid >> 3, c0 = (tid & 7) * 8;
    const float* src = Q + base + (size_t)(qt * 32 + r) * 512 + c0;
    float4 t0 = *(const float4*)src, t1 = *(const float4*)(src + 4);
    Qs[r][c0+0] = t0.x; Qs[r][c0+1] = t0.y; Qs[r][c0+2] = t0.z; Qs[r][c0+3] = t0.w;
    Qs[r][c0+4] = t1.x; Qs[r][c0+5] = t1.y; Qs[r][c0+6] = t1.z; Qs[r][c0+7] = t1.w;
  }
  if (tid < 32) { mrow[tid] = -1e30f; lrow[tid] = 0.f; }
  float o[2][4] = {};
  const int ktmax = (qt * 32 + 31) >> 6;  // inclusive

  for (int kt = 0; kt <= ktmax; ++kt) {
    __syncthreads();
    {
      const int r = tid >> 2, c0 = (tid & 3) * 16;
      const float* ks = K + base + (size_t)(kt * 64 + r) * 512 + c0;
      const float* vs = V + base + (size_t)(kt * 64 + r) * 512 + c0;
#pragma unroll
      for (int i = 0; i < 16; i += 4) {
        float4 t = *(const float4*)(ks + i);
        Ks[r][c0+i] = t.x; Ks[r][c0+i+1] = t.y; Ks[r][c0+i+2] = t.z; Ks[r][c0+i+3] = t.w;
      }
#pragma unroll
      for (int i = 0; i < 16; i += 4) {
        float4 t = *(const float4*)(vs + i);
        Vs[r][c0+i] = t.x; Vs[r][c0+i+1] = t.y; Vs[r][c0+i+2] = t.z; Vs[r][c0+i+3] = t.w;
      }
    }
    __syncthreads();

    float s[2][4] = {};
#pragma unroll 4
    for (int d = 0; d < 64; ++d) {
      const float q0 = Qs[ty2][d], q1 = Qs[ty2 + 1][d];
      const float k0 = Ks[tx4][d], k1 = Ks[tx4+1][d], k2 = Ks[tx4+2][d], k3 = Ks[tx4+3][d];
      s[0][0] += q0*k0; s[0][1] += q0*k1; s[0][2] += q0*k2; s[0][3] += q0*k3;
      s[1][0] += q1*k0; s[1][1] += q1*k1; s[1][2] += q1*k2; s[1][3] += q1*k3;
    }
    const int qg0 = qt * 32 + ty2;
    const int kg0 = kt * 64 + tx4;
#pragma unroll
    for (int i = 0; i < 2; ++i)
#pragma unroll
      for (int j = 0; j < 4; ++j) {
        float v = s[i][j] * 0.125f;
        if (kg0 + j > qg0 + i) v = -1e30f;
        s[i][j] = v;
      }
    float pm0 = fmaxf(fmaxf(s[0][0], s[0][1]), fmaxf(s[0][2], s[0][3]));
    float pm1 = fmaxf(fmaxf(s[1][0], s[1][1]), fmaxf(s[1][2], s[1][3]));
    red[ty2][tx] = pm0; red[ty2 + 1][tx] = pm1;
    __syncthreads();
    if (tid < 32) {
      float mo = mrow[tid], mn = mo;
#pragma unroll
      for (int t = 0; t < 16; ++t) mn = fmaxf(mn, red[tid][t]);
      const float al = __expf(mo - mn);
      arow[tid] = al; lrow[tid] *= al; mrow[tid] = mn;
    }
    __syncthreads();
    const float m0v = mrow[ty2], m1v = mrow[ty2 + 1];
    float ps0 = 0.f, ps1 = 0.f;
#pragma unroll
    for (int j = 0; j < 4; ++j) {
      float p0 = __expf(s[0][j] - m0v);
      float p1 = __expf(s[1][j] - m1v);
      Ps[ty2][tx4 + j] = p0; Ps[ty2 + 1][tx4 + j] = p1;
      ps0 += p0; ps1 += p1;
    }
    red[ty2][tx] = ps0; red[ty2 + 1][tx] = ps1;
    __syncthreads();
    if (tid < 32) {
      float t = 0.f;
#pragma unroll
      for (int u = 0; u < 16; ++u) t += red[tid][u];
      lrow[tid] += t;
    }
    const float a0 = arow[ty2], a1 = arow[ty2 + 1];
#pragma unroll
    for (int j = 0; j < 4; ++j) { o[0][j] *= a0; o[1][j] *= a1; }
#pragma unroll 4
    for (int c = 0; c < 64; ++c) {
      const float p0 = Ps[ty2][c], p1 = Ps[ty2 + 1][c];
      const float v0 = Vs[c][tx4], v1 = Vs[c][tx4+1], v2 = Vs[c][tx4+2], v3 = Vs[c][tx4+3];
      o[0][0] += p0*v0; o[0][1] += p0*v1; o[0][2] += p0*v2; o[0][3] += p0*v3;
      o[1][0] += p1*v0; o[1][1] += p1*v1; o[1][2] += p1*v2; o[1][3] += p1*v3;
    }
  }
  __syncthreads();
  const float il0 = 1.f / lrow[ty2], il1 = 1.f / lrow[ty2 + 1];
  ushort4 u0, u1;
  u0.x = f2bf(o[0][0]*il0); u0.y = f2bf(o[0][1]*il0); u0.z = f2bf(o[0][2]*il0); u0.w = f2bf(o[0][3]*il0);
  u1.x = f2bf(o[1][0]*il1); u1.y = f2bf(o[1][1]*il1); u1.z = f2bf(o[1][2]*il1); u1.w = f2bf(o[1][3]*il1);
  ushort* dst0 = Obf + base + (size_t)(qt * 32 + ty2) * 512 + tx4;
  *(ushort4*)dst0 = u0;
  *(ushort4*)(dst0 + 512) = u1;
}

// ---------------------------------------------------------------------------
// Cross-attention over 11 slots + cross_sum accumulation (head-mean, x1/8).
// grid (8 row-tiles of 128, 64 b*h), block 128 (one thread per q row)
// ---------------------------------------------------------------------------
__launch_bounds__(128)
__global__ void attn_cross(const float* __restrict__ Q, const float* __restrict__ Kc,
                           const float* __restrict__ Vc, ushort* __restrict__ Obf,
                           float* __restrict__ csum) {
  const int rt = blockIdx.x;
  const int bh = blockIdx.y;
  const int b = bh >> 3, h = bh & 7;
  const int tid = threadIdx.x;
  __shared__ float Qs[128][65];
  __shared__ float Kcs[11][64];
  __shared__ float Vcs[11][64];
  const size_t base = ((size_t)(b * 1024)) * 512 + h * 64;

  for (int i = tid; i < 704; i += 128) {
    const int k = i >> 6, d = i & 63;
    Kcs[k][d] = Kc[((size_t)(b * 11 + k)) * 512 + h * 64 + d];
    Vcs[k][d] = Vc[((size_t)(b * 11 + k)) * 512 + h * 64 + d];
  }
#pragma unroll
  for (int it = 0; it < 16; ++it) {
    const int idx = tid + 128 * it;
    const int r = idx >> 4, c = (idx & 15) * 4;
    float4 t = *(const float4*)(Q + base + (size_t)(rt * 128 + r) * 512 + c);
    Qs[r][c] = t.x; Qs[r][c+1] = t.y; Qs[r][c+2] = t.z; Qs[r][c+3] = t.w;
  }
  __syncthreads();

  float s[11] = {};
  for (int d = 0; d < 64; ++d) {
    const float qv = Qs[tid][d];
#pragma unroll
    for (int k = 0; k < 11; ++k) s[k] += qv * Kcs[k][d];
  }
  float m = s[0] * 0.125f;
#pragma unroll
  for (int k = 0; k < 11; ++k) { s[k] *= 0.125f; m = fmaxf(m, s[k]); }
  float l = 0.f;
#pragma unroll
  for (int k = 0; k < 11; ++k) { s[k] = __expf(s[k] - m); l += s[k]; }
  const float inv = 1.f / l;
#pragma unroll
  for (int k = 0; k < 11; ++k) s[k] *= inv;

  const int qrow = rt * 128 + tid;
  float* cs = csum + ((size_t)(b * 1024 + qrow)) * 11;
#pragma unroll
  for (int k = 0; k < 11; ++k) atomicAdd(cs + k, s[k] * 0.125f);

  ushort* dst = Obf + base + (size_t)qrow * 512;
  for (int d = 0; d < 64; ++d) {
    float acc = 0.f;
#pragma unroll
    for (int k = 0; k < 11; ++k) acc += s[k] * Vcs[k][d];
    dst[d] = f2bf(acc);
  }
}

// ---------------------------------------------------------------------------
// Final output: d_out = [tokens (8*1024*512 f32), masks = csum/4 (8*1024*11)]
// ---------------------------------------------------------------------------
__global__ void finalize(const float* __restrict__ tokens, const float* __restrict__ csum,
                         float* __restrict__ out) {
  const int i = blockIdx.x * 256 + threadIdx.x;
  if (i < 4194304) out[i] = tokens[i];
  else if (i < 4284416) out[i] = csum[i - 4194304] * 0.25f;
}

// ---------------------------------------------------------------------------
// Host
// ---------------------------------------------------------------------------
extern "C" void kernel_launch(void* const* d_in, const int* in_sizes, int n_in,
                              void* d_out, int out_size, void* d_ws, size_t ws_size,
                              hipStream_t stream) {
  const float* features = (const float*)d_in[0];
  const float* slots    = (const float*)d_in[1];
  const float* tok_w    = (const float*)d_in[2];
  const float* tok_b    = (const float*)d_in[3];
  const float* slot_g   = (const float*)d_in[4];
  const float* slot_b   = (const float*)d_in[5];
  const float* ln1_g    = (const float*)d_in[6];
  const float* ln1_b    = (const float*)d_in[7];
  const float* ln2_g    = (const float*)d_in[8];
  const float* ln2_b    = (const float*)d_in[9];
  const float* ln3_g    = (const float*)d_in[10];
  const float* ln3_b    = (const float*)d_in[11];
  const float* sa_qw = (const float*)d_in[12]; const float* sa_qb = (const float*)d_in[13];
  const float* sa_kw = (const float*)d_in[14]; const float* sa_kb = (const float*)d_in[15];
  const float* sa_vw = (const float*)d_in[16]; const float* sa_vb = (const float*)d_in[17];
  const float* sa_ow = (const float*)d_in[18]; const float* sa_ob = (const float*)d_in[19];
  const float* ca_qw = (const float*)d_in[20]; const float* ca_qb = (const float*)d_in[21];
  const float* ca_kw = (const float*)d_in[22]; const float* ca_kb = (const float*)d_in[23];
  const float* ca_vw = (const float*)d_in[24]; const float* ca_vb = (const float*)d_in[25];
  const float* ca_ow = (const float*)d_in[26]; const float* ca_ob = (const float*)d_in[27];
  const float* ffn_w1 = (const float*)d_in[28]; const float* ffn_b1 = (const float*)d_in[29];
  const float* ffn_w2 = (const float*)d_in[30]; const float* ffn_b2 = (const float*)d_in[31];

  // workspace carve (256B aligned)
  char* wp = (char*)d_ws;
  size_t off = 0;
  auto carve = [&](size_t bytes) -> void* {
    void* p = wp + off;
    off = (off + bytes + 255) & ~(size_t)255;
    return p;
  };
  float*  tokens  = (float*)carve(8192ull * 512 * 4);
  ushort* hbf     = (ushort*)carve(8192ull * 512 * 2);
  float*  qf      = (float*)carve(8192ull * 512 * 4);
  float*  kf      = (float*)carve(8192ull * 512 * 4);
  float*  vf      = (float*)carve(8192ull * 512 * 4);
  ushort* cbf     = (ushort*)carve(8192ull * 512 * 2);
  ushort* hidbf   = (ushort*)carve(8192ull * 2048 * 2);  // also reused for features-bf16
  float*  slotsn  = (float*)carve(88ull * 512 * 4);
  float*  kc      = (float*)carve(88ull * 512 * 4);
  float*  vc      = (float*)carve(88ull * 512 * 4);
  float*  csum    = (float*)carve(8ull * 1024 * 11 * 4);
  ushort* tokwbf  = (ushort*)carve(512ull * 768 * 2);
  ushort* saqwbf  = (ushort*)carve(4ull * 512 * 512 * 2);
  ushort* sakwbf  = (ushort*)carve(4ull * 512 * 512 * 2);
  ushort* savwbf  = (ushort*)carve(4ull * 512 * 512 * 2);
  ushort* saowbf  = (ushort*)carve(4ull * 512 * 512 * 2);
  ushort* caqwbf  = (ushort*)carve(4ull * 512 * 512 * 2);
  ushort* caowbf  = (ushort*)carve(4ull * 512 * 512 * 2);
  ushort* w1bf    = (ushort*)carve(4ull * 2048 * 512 * 2);
  ushort* w2bf    = (ushort*)carve(4ull * 512 * 2048 * 2);
  ushort* featbf  = hidbf;  // alias: features-bf consumed before ffn hidden is produced

  auto conv = [&](const float* s, ushort* d, int n) {
    const int n4 = n / 4;
    f32_to_bf16_vec<<<(n4 + 255) / 256, 256, 0, stream>>>(s, d, n4);
  };
  conv(features, featbf, 8192 * 768);
  conv(tok_w,  tokwbf, 512 * 768);
  conv(sa_qw,  saqwbf, 4 * 512 * 512);
  conv(sa_kw,  sakwbf, 4 * 512 * 512);
  conv(sa_vw,  savwbf, 4 * 512 * 512);
  conv(sa_ow,  saowbf, 4 * 512 * 512);
  conv(ca_qw,  caqwbf, 4 * 512 * 512);
  conv(ca_ow,  caowbf, 4 * 512 * 512);
  conv(ffn_w1, w1bf,   4 * 2048 * 512);
  conv(ffn_w2, w2bf,   4 * 512 * 2048);

  hipMemsetAsync(csum, 0, 8ull * 1024 * 11 * 4, stream);

  // token embedding: tokens = features @ tok_w^T + tok_b
  gemm_bt<0><<<dim3(4, 64), 256, 0, stream>>>(featbf, tokwbf, tok_b, tokens, (ushort*)nullptr, 8192, 512, 768);
  // slots_n = LN(slots)
  ln512<0><<<22, 256, 0, stream>>>(slots, slot_g, slot_b, slotsn, 88);

  for (int l = 0; l < 4; ++l) {
    const size_t wD = (size_t)l * 512 * 512;
    const size_t bD = (size_t)l * 512;
    // ---- self attention ----
    ln512<1><<<2048, 256, 0, stream>>>(tokens, ln1_g + bD, ln1_b + bD, hbf, 8192);
    gemm_bt<0><<<dim3(4, 64), 256, 0, stream>>>(hbf, saqwbf + wD, sa_qb + bD, qf, (ushort*)nullptr, 8192, 512, 512);
    gemm_bt<0><<<dim3(4, 64), 256, 0, stream>>>(hbf, sakwbf + wD, sa_kb + bD, kf, (ushort*)nullptr, 8192, 512, 512);
    gemm_bt<0><<<dim3(4, 64), 256, 0, stream>>>(hbf, savwbf + wD, sa_vb + bD, vf, (ushort*)nullptr, 8192, 512, 512);
    l2norm64<<<16384, 256, 0, stream>>>(qf, 65536);
    l2norm64<<<16384, 256, 0, stream>>>(kf, 65536);
    attn_self<<<dim3(32, 64), 256, 0, stream>>>(qf, kf, vf, cbf);
    gemm_bt<1><<<dim3(4, 64), 256, 0, stream>>>(cbf, saowbf + wD, sa_ob + bD, tokens, (ushort*)nullptr, 8192, 512, 512);
    // ---- cross attention ----
    ln512<1><<<2048, 256, 0, stream>>>(tokens, ln2_g + bD, ln2_b + bD, hbf, 8192);
    gemm_bt<0><<<dim3(4, 64), 256, 0, stream>>>(hbf, caqwbf + wD, ca_qb + bD, qf, (ushort*)nullptr, 8192, 512, 512);
    gemm88<<<88, 256, 0, stream>>>(slotsn, ca_kw + wD, ca_kb + bD, kc);
    gemm88<<<88, 256, 0, stream>>>(slotsn, ca_vw + wD, ca_vb + bD, vc);
    l2norm64<<<16384, 256, 0, stream>>>(qf, 65536);
    l2norm64<<<176, 256, 0, stream>>>(kc, 704);
    attn_cross<<<dim3(8, 64), 128, 0, stream>>>(qf, kc, vc, cbf, csum);
    gemm_bt<1><<<dim3(4, 64), 256, 0, stream>>>(cbf, caowbf + wD, ca_ob + bD, tokens, (ushort*)nullptr, 8192, 512, 512);
    // ---- FFN ----
    const size_t wM = (size_t)l * 2048 * 512;
    const size_t bM = (size_t)l * 2048;
    ln512<1><<<2048, 256, 0, stream>>>(tokens, ln3_g + bD, ln3_b + bD, hbf, 8192);
    gemm_bt<2><<<dim3(16, 64), 256, 0, stream>>>(hbf, w1bf + wM, ffn_b1 + bM, (float*)nullptr, hidbf, 8192, 2048, 512);
    gemm_bt<1><<<dim3(4, 64), 256, 0, stream>>>(hidbf, w2bf + wM, ffn_b2 + bD, tokens, (ushort*)nullptr, 8192, 512, 2048);
  }

  finalize<<<16736, 256, 0, stream>>>(tokens, csum, (float*)d_out);
}

// Round 2
// 1858.627 us; speedup vs baseline: 2.0741x; 2.0741x over previous
//
#include <hip/hip_runtime.h>
#include <math.h>

#define DEV __device__ __forceinline__

typedef __attribute__((ext_vector_type(4))) float f32x4;
typedef __attribute__((ext_vector_type(8))) short bf16x8;

DEV ushort f2bf(float x) {
  unsigned u = __float_as_uint(x);
  u = (u + 0x7FFFu + ((u >> 16) & 1u)) >> 16;
  return (ushort)u;
}

DEV float bf2f(ushort u) { return __uint_as_float(((unsigned)u) << 16); }

DEV float gelu_exact(float x) {
  return 0.5f * x * (1.0f + erff(x * 0.70710678118654752f));
}

DEV void async16(const void* g, void* l) {
  __builtin_amdgcn_global_load_lds((const __attribute__((address_space(1))) void*)g,
                                   (__attribute__((address_space(3))) void*)l, 16, 0, 0);
}

// ---------------------------------------------------------------------------
// f32 -> bf16 elementwise convert (n divisible by 4)
// ---------------------------------------------------------------------------
__global__ void f32_to_bf16_vec(const float* __restrict__ src, ushort* __restrict__ dst, int n4) {
  int i = blockIdx.x * 256 + threadIdx.x;
  if (i < n4) {
    float4 f = ((const float4*)src)[i];
    ushort4 u;
    u.x = f2bf(f.x); u.y = f2bf(f.y); u.z = f2bf(f.z); u.w = f2bf(f.w);
    ((ushort4*)dst)[i] = u;
  }
}

// ---------------------------------------------------------------------------
// bf16 GEMM:  Y[M,N] = A[M,K] @ W[N,K]^T + bias   (m97 structure)
// EPI 0: Yf = val           1: Yf += val
// EPI 2: Ybf = bf16(gelu)   3: Ybf = bf16(val)
// EPI 4: per-head (64-col) l2norm, Ybf = bf16(val/max(||row_head||,1e-6))
// M%128==0, N%128==0, K%32==0. For EPI 4, head boundaries at n%64==0.
// ---------------------------------------------------------------------------
template <int EPI>
__launch_bounds__(256, 2)
__global__ void gemm_bt(const ushort* __restrict__ A, const ushort* __restrict__ W,
                        const float* __restrict__ bias, float* __restrict__ Yf,
                        ushort* __restrict__ Ybf, int M, int N, int K) {
  __shared__ ushort As[128 * 32];
  __shared__ ushort Bs[128 * 32];
  const int tid  = threadIdx.x;
  const int lane = tid & 63;
  const int wave = tid >> 6;
  const int wr = wave >> 1, wc = wave & 1;
  const int m0 = blockIdx.y * 128, n0 = blockIdx.x * 128;
  const int q = lane >> 4, ln = lane & 15;
  const int srow = lane >> 2;
  const int scol = (lane & 3) * 8;

  f32x4 acc[4][4] = {};

  const ushort* gA = A + (size_t)(m0 + wave * 32 + srow) * K + scol;
  const ushort* gB = W + (size_t)(n0 + wave * 32 + srow) * K + scol;
  ushort* lA = &As[(wave * 32) * 32];
  ushort* lB = &Bs[(wave * 32) * 32];

  for (int k0 = 0; k0 < K; k0 += 32) {
    async16(gA + k0, lA);
    async16(gA + k0 + (size_t)16 * K, lA + 16 * 32);
    async16(gB + k0, lB);
    async16(gB + k0 + (size_t)16 * K, lB + 16 * 32);
    __syncthreads();
    bf16x8 af[4], bfr[4];
#pragma unroll
    for (int t = 0; t < 4; ++t)
      af[t] = *(const bf16x8*)&As[(wr * 64 + t * 16 + ln) * 32 + q * 8];
#pragma unroll
    for (int t = 0; t < 4; ++t)
      bfr[t] = *(const bf16x8*)&Bs[(wc * 64 + t * 16 + ln) * 32 + q * 8];
#pragma unroll
    for (int mt = 0; mt < 4; ++mt)
#pragma unroll
      for (int nt = 0; nt < 4; ++nt)
        acc[mt][nt] = __builtin_amdgcn_mfma_f32_16x16x32_bf16(af[mt], bfr[nt], acc[mt][nt], 0, 0, 0);
    __syncthreads();
  }

  if (EPI == 4) {
    // fused bias + per-head l2norm + bf16 store. Wave's 64 n-cols = one head.
#pragma unroll
    for (int mt = 0; mt < 4; ++mt) {
      const int gm = m0 + wr * 64 + mt * 16 + q * 4;
      float val[4][4];  // [nt][r]
#pragma unroll
      for (int nt = 0; nt < 4; ++nt) {
        const float bi = bias[n0 + wc * 64 + nt * 16 + ln];
#pragma unroll
        for (int r = 0; r < 4; ++r) val[nt][r] = acc[mt][nt][r] + bi;
      }
#pragma unroll
      for (int r = 0; r < 4; ++r) {
        float ss = val[0][r]*val[0][r] + val[1][r]*val[1][r] +
                   val[2][r]*val[2][r] + val[3][r]*val[3][r];
        ss += __shfl_xor(ss, 1);
        ss += __shfl_xor(ss, 2);
        ss += __shfl_xor(ss, 4);
        ss += __shfl_xor(ss, 8);
        const float inv = 1.f / fmaxf(sqrtf(ss), 1e-6f);
#pragma unroll
        for (int nt = 0; nt < 4; ++nt) {
          const int gn = n0 + wc * 64 + nt * 16 + ln;
          Ybf[(size_t)(gm + r) * N + gn] = f2bf(val[nt][r] * inv);
        }
      }
    }
  } else {
#pragma unroll
    for (int mt = 0; mt < 4; ++mt) {
      const int gm = m0 + wr * 64 + mt * 16 + q * 4;
#pragma unroll
      for (int nt = 0; nt < 4; ++nt) {
        const int gn = n0 + wc * 64 + nt * 16 + ln;
        const float bi = bias[gn];
#pragma unroll
        for (int r = 0; r < 4; ++r) {
          const float val = acc[mt][nt][r] + bi;
          const size_t idx = (size_t)(gm + r) * N + gn;
          if (EPI == 0)      Yf[idx] = val;
          else if (EPI == 1) Yf[idx] += val;
          else if (EPI == 2) Ybf[idx] = f2bf(gelu_exact(val));
          else               Ybf[idx] = f2bf(val);
        }
      }
    }
  }
}

// ---------------------------------------------------------------------------
// LayerNorm over D=512, one wave per row. BF=1: bf16 out, BF=0: f32 out
// ---------------------------------------------------------------------------
template <int BF>
__launch_bounds__(256)
__global__ void ln512(const float* __restrict__ X, const float* __restrict__ G,
                      const float* __restrict__ Bb, void* __restrict__ Yv, int rows) {
  const int lane = threadIdx.x & 63;
  const int wave = threadIdx.x >> 6;
  const int row = blockIdx.x * 4 + wave;
  if (row >= rows) return;
  const float* x = X + (size_t)row * 512 + lane * 8;
  float4 v0 = *(const float4*)x;
  float4 v1 = *(const float4*)(x + 4);
  float s = v0.x + v0.y + v0.z + v0.w + v1.x + v1.y + v1.z + v1.w;
#pragma unroll
  for (int off = 32; off; off >>= 1) s += __shfl_xor(s, off);
  const float mean = s * (1.f / 512.f);
  float d[8] = {v0.x - mean, v0.y - mean, v0.z - mean, v0.w - mean,
                v1.x - mean, v1.y - mean, v1.z - mean, v1.w - mean};
  float ss = d[0]*d[0] + d[1]*d[1] + d[2]*d[2] + d[3]*d[3] +
             d[4]*d[4] + d[5]*d[5] + d[6]*d[6] + d[7]*d[7];
#pragma unroll
  for (int off = 32; off; off >>= 1) ss += __shfl_xor(ss, off);
  const float rstd = rsqrtf(ss * (1.f / 512.f) + 1e-5f);
  const float* gp = G + lane * 8;
  const float* bp = Bb + lane * 8;
  float4 g0 = *(const float4*)gp, g1 = *(const float4*)(gp + 4);
  float4 b0 = *(const float4*)bp, b1 = *(const float4*)(bp + 4);
  float y[8];
  y[0] = d[0]*rstd*g0.x + b0.x; y[1] = d[1]*rstd*g0.y + b0.y;
  y[2] = d[2]*rstd*g0.z + b0.z; y[3] = d[3]*rstd*g0.w + b0.w;
  y[4] = d[4]*rstd*g1.x + b1.x; y[5] = d[5]*rstd*g1.y + b1.y;
  y[6] = d[6]*rstd*g1.z + b1.z; y[7] = d[7]*rstd*g1.w + b1.w;
  if (BF) {
    ushort* o = (ushort*)Yv + (size_t)row * 512 + lane * 8;
    ushort4 u0, u1;
    u0.x = f2bf(y[0]); u0.y = f2bf(y[1]); u0.z = f2bf(y[2]); u0.w = f2bf(y[3]);
    u1.x = f2bf(y[4]); u1.y = f2bf(y[5]); u1.z = f2bf(y[6]); u1.w = f2bf(y[7]);
    *(ushort4*)o = u0; *(ushort4*)(o + 4) = u1;
  } else {
    float* o = (float*)Yv + (size_t)row * 512 + lane * 8;
    *(float4*)o = make_float4(y[0], y[1], y[2], y[3]);
    *(float4*)(o + 4) = make_float4(y[4], y[5], y[6], y[7]);
  }
}

// ---------------------------------------------------------------------------
// In-place L2 normalize contiguous segments of 64 floats (cross-attn K only)
// ---------------------------------------------------------------------------
__launch_bounds__(256)
__global__ void l2norm64(float* __restrict__ X, int nseg) {
  const int seg = blockIdx.x * 4 + (threadIdx.x >> 6);
  const int lane = threadIdx.x & 63;
  if (seg >= nseg) return;
  float v = X[(size_t)seg * 64 + lane];
  float ss = v * v;
#pragma unroll
  for (int off = 32; off; off >>= 1) ss += __shfl_xor(ss, off);
  const float n = sqrtf(ss);
  X[(size_t)seg * 64 + lane] = v / fmaxf(n, 1e-6f);
}

// ---------------------------------------------------------------------------
// Small fp32 GEMM for slot K/V projections: Y[88,512] = X[88,512]@W[512,512]^T+b
// ---------------------------------------------------------------------------
__launch_bounds__(256)
__global__ void gemm88(const float* __restrict__ X, const float* __restrict__ W,
                       const float* __restrict__ bias, float* __restrict__ Y) {
  const int m = blockIdx.x;
  const int tid = threadIdx.x;
  __shared__ float xs[512];
  xs[tid] = X[(size_t)m * 512 + tid];
  xs[tid + 256] = X[(size_t)m * 512 + tid + 256];
  __syncthreads();
#pragma unroll
  for (int rep = 0; rep < 2; ++rep) {
    const int n = tid + rep * 256;
    const float* wr = W + (size_t)n * 512;
    float acc = bias[n];
    for (int k = 0; k < 512; k += 4) {
      float4 w4 = *(const float4*)(wr + k);
      acc += xs[k] * w4.x + xs[k+1] * w4.y + xs[k+2] * w4.z + xs[k+3] * w4.w;
    }
    Y[(size_t)m * 512 + n] = acc;
  }
}

// ---------------------------------------------------------------------------
// Causal self-attention, MFMA flash-style, bf16 in/out.
// grid (16 qtiles of 64, 64 b*h), block 256 = 4 waves; wave w owns q rows w*16..
// QK^T and PV via mfma_f32_16x16x32_bf16. P round-trips per-wave LDS
// (C-layout -> A-layout). V staged transposed. Softmax state in registers.
// ---------------------------------------------------------------------------
__launch_bounds__(256, 2)
__global__ void attn_self_mfma(const ushort* __restrict__ Q, const ushort* __restrict__ K,
                               const ushort* __restrict__ V, ushort* __restrict__ O) {
  constexpr int LDK = 72;  // row stride in ushorts (144 B, 16B-aligned, conflict-light)
  __shared__ ushort Qs[64 * LDK];
  __shared__ ushort Ks[64 * LDK];
  __shared__ ushort Vt[64 * LDK];      // transposed: [d][k]
  __shared__ ushort Ps[4][16 * LDK];   // per-wave P scratch [q][k]
  const int qt = blockIdx.x, bh = blockIdx.y;
  const int b = bh >> 3, h = bh & 7;
  const size_t base = (size_t)b * 1024 * 512 + h * 64;
  const int tid = threadIdx.x;
  const int lane = tid & 63, wave = tid >> 6;
  const int quad = lane >> 4, ln = lane & 15;

  // stage Q tile (64 rows x 64 d)
  {
    const int r = tid >> 2, c0 = (tid & 3) * 16;
    const ushort* src = Q + base + (size_t)(qt * 64 + r) * 512 + c0;
    *(uint4*)&Qs[r * LDK + c0]     = *(const uint4*)src;
    *(uint4*)&Qs[r * LDK + c0 + 8] = *(const uint4*)(src + 8);
  }
  __syncthreads();
  bf16x8 qf[2];
  qf[0] = *(const bf16x8*)&Qs[(wave * 16 + ln) * LDK + quad * 8];
  qf[1] = *(const bf16x8*)&Qs[(wave * 16 + ln) * LDK + 32 + quad * 8];

  float m_r[4], l_r[4];
  f32x4 o_acc[4] = {};
#pragma unroll
  for (int r = 0; r < 4; ++r) { m_r[r] = -1e30f; l_r[r] = 0.f; }

  for (int kt = 0; kt <= qt; ++kt) {
    __syncthreads();  // previous tile's frags consumed
    {
      const int r = tid >> 2, c0 = (tid & 3) * 16;
      const ushort* src = K + base + (size_t)(kt * 64 + r) * 512 + c0;
      *(uint4*)&Ks[r * LDK + c0]     = *(const uint4*)src;
      *(uint4*)&Ks[r * LDK + c0 + 8] = *(const uint4*)(src + 8);
      // V transposed: thread (k=lane, d0=wave*16) writes 16 scalars
      const int kk = lane, d0 = wave * 16;
      const ushort* vsrc = V + base + (size_t)(kt * 64 + kk) * 512 + d0;
      ushort vv[16];
      *(uint4*)vv       = *(const uint4*)vsrc;
      *(uint4*)(vv + 8) = *(const uint4*)(vsrc + 8);
#pragma unroll
      for (int j = 0; j < 16; ++j) Vt[(d0 + j) * LDK + kk] = vv[j];
    }
    __syncthreads();

    // S = Q K^T  (16q x 64k per wave)
    f32x4 s[4] = {};
#pragma unroll
    for (int kb = 0; kb < 4; ++kb) {
      bf16x8 kf0 = *(const bf16x8*)&Ks[(kb * 16 + ln) * LDK + quad * 8];
      bf16x8 kf1 = *(const bf16x8*)&Ks[(kb * 16 + ln) * LDK + 32 + quad * 8];
      s[kb] = __builtin_amdgcn_mfma_f32_16x16x32_bf16(qf[0], kf0, s[kb], 0, 0, 0);
      s[kb] = __builtin_amdgcn_mfma_f32_16x16x32_bf16(qf[1], kf1, s[kb], 0, 0, 0);
    }
    const int qrow0 = qt * 64 + wave * 16 + quad * 4;  // + r
#pragma unroll
    for (int kb = 0; kb < 4; ++kb) {
#pragma unroll
      for (int r = 0; r < 4; ++r) s[kb][r] *= 0.125f;
    }
    if (kt == qt) {
#pragma unroll
      for (int kb = 0; kb < 4; ++kb) {
        const int kcol = kt * 64 + kb * 16 + ln;
#pragma unroll
        for (int r = 0; r < 4; ++r)
          if (kcol > qrow0 + r) s[kb][r] = -1e30f;
      }
    }

    // online softmax (per-row state replicated across the 16-lane group)
    float mnew[4], alpha[4];
#pragma unroll
    for (int r = 0; r < 4; ++r) {
      float mx = fmaxf(fmaxf(s[0][r], s[1][r]), fmaxf(s[2][r], s[3][r]));
      mx = fmaxf(mx, __shfl_xor(mx, 1));
      mx = fmaxf(mx, __shfl_xor(mx, 2));
      mx = fmaxf(mx, __shfl_xor(mx, 4));
      mx = fmaxf(mx, __shfl_xor(mx, 8));
      mnew[r] = fmaxf(m_r[r], mx);
      alpha[r] = __expf(m_r[r] - mnew[r]);
      m_r[r] = mnew[r];
    }
#pragma unroll
    for (int r = 0; r < 4; ++r) {
      float sum = 0.f;
#pragma unroll
      for (int kb = 0; kb < 4; ++kb) {
        const float p = __expf(s[kb][r] - mnew[r]);
        sum += p;
        Ps[wave][(quad * 4 + r) * LDK + kb * 16 + ln] = f2bf(p);
      }
      sum += __shfl_xor(sum, 1);
      sum += __shfl_xor(sum, 2);
      sum += __shfl_xor(sum, 4);
      sum += __shfl_xor(sum, 8);
      l_r[r] = l_r[r] * alpha[r] + sum;
#pragma unroll
      for (int db = 0; db < 4; ++db) o_acc[db][r] *= alpha[r];
    }
    __builtin_amdgcn_wave_barrier();  // keep P write -> read ordering (intra-wave, in-order LDS)

    // O += P V   (A-frags of P from LDS, B-frags from Vt rows)
    bf16x8 pf0 = *(const bf16x8*)&Ps[wave][ln * LDK + quad * 8];
    bf16x8 pf1 = *(const bf16x8*)&Ps[wave][ln * LDK + 32 + quad * 8];
#pragma unroll
    for (int db = 0; db < 4; ++db) {
      bf16x8 vf0 = *(const bf16x8*)&Vt[(db * 16 + ln) * LDK + quad * 8];
      bf16x8 vf1 = *(const bf16x8*)&Vt[(db * 16 + ln) * LDK + 32 + quad * 8];
      o_acc[db] = __builtin_amdgcn_mfma_f32_16x16x32_bf16(pf0, vf0, o_acc[db], 0, 0, 0);
      o_acc[db] = __builtin_amdgcn_mfma_f32_16x16x32_bf16(pf1, vf1, o_acc[db], 0, 0, 0);
    }
  }

  // epilogue: O / l -> bf16
  const int qrow0 = qt * 64 + wave * 16 + quad * 4;
#pragma unroll
  for (int r = 0; r < 4; ++r) {
    const float inv = 1.f / l_r[r];
    ushort* dst = O + base + (size_t)(qrow0 + r) * 512;
#pragma unroll
    for (int db = 0; db < 4; ++db)
      dst[db * 16 + ln] = f2bf(o_acc[db][r] * inv);
  }
}

// ---------------------------------------------------------------------------
// Cross-attention over 11 slots + cross_sum accumulation (head-mean, x1/8).
// Q is bf16 (already l2-normalized). grid (8 tiles of 128, 64 b*h), block 128.
// ---------------------------------------------------------------------------
__launch_bounds__(128)
__global__ void attn_cross(const ushort* __restrict__ Q, const float* __restrict__ Kc,
                           const float* __restrict__ Vc, ushort* __restrict__ Obf,
                           float* __restrict__ csum) {
  const int rt = blockIdx.x;
  const int bh = blockIdx.y;
  const int b = bh >> 3, h = bh & 7;
  const int tid = threadIdx.x;
  __shared__ float Qs[128][65];
  __shared__ float Kcs[11][64];
  __shared__ float Vcs[11][64];
  const size_t base = ((size_t)(b * 1024)) * 512 + h * 64;

  for (int i = tid; i < 704; i += 128) {
    const int k = i >> 6, d = i & 63;
    Kcs[k][d] = Kc[((size_t)(b * 11 + k)) * 512 + h * 64 + d];
    Vcs[k][d] = Vc[((size_t)(b * 11 + k)) * 512 + h * 64 + d];
  }
#pragma unroll
  for (int it = 0; it < 8; ++it) {
    const int idx = tid + 128 * it;          // 1024 chunks of 8 ushorts
    const int r = idx >> 3, c = (idx & 7) * 8;
    uint4 t = *(const uint4*)(Q + base + (size_t)(rt * 128 + r) * 512 + c);
    const ushort* u = (const ushort*)&t;
#pragma unroll
    for (int j = 0; j < 8; ++j) Qs[r][c + j] = bf2f(u[j]);
  }
  __syncthreads();

  float s[11] = {};
  for (int d = 0; d < 64; ++d) {
    const float qv = Qs[tid][d];
#pragma unroll
    for (int k = 0; k < 11; ++k) s[k] += qv * Kcs[k][d];
  }
  float m = s[0] * 0.125f;
#pragma unroll
  for (int k = 0; k < 11; ++k) { s[k] *= 0.125f; m = fmaxf(m, s[k]); }
  float l = 0.f;
#pragma unroll
  for (int k = 0; k < 11; ++k) { s[k] = __expf(s[k] - m); l += s[k]; }
  const float inv = 1.f / l;
#pragma unroll
  for (int k = 0; k < 11; ++k) s[k] *= inv;

  const int qrow = rt * 128 + tid;
  float* cs = csum + ((size_t)(b * 1024 + qrow)) * 11;
#pragma unroll
  for (int k = 0; k < 11; ++k) atomicAdd(cs + k, s[k] * 0.125f);

  ushort* dst = Obf + base + (size_t)qrow * 512;
  for (int d = 0; d < 64; ++d) {
    float acc = 0.f;
#pragma unroll
    for (int k = 0; k < 11; ++k) acc += s[k] * Vcs[k][d];
    dst[d] = f2bf(acc);
  }
}

// ---------------------------------------------------------------------------
// Final output: d_out = [tokens (8*1024*512 f32), masks = csum/4 (8*1024*11)]
// ---------------------------------------------------------------------------
__global__ void finalize(const float* __restrict__ tokens, const float* __restrict__ csum,
                         float* __restrict__ out) {
  const int i = blockIdx.x * 256 + threadIdx.x;
  if (i < 4194304) out[i] = tokens[i];
  else if (i < 4284416) out[i] = csum[i - 4194304] * 0.25f;
}

// ---------------------------------------------------------------------------
// Host
// ---------------------------------------------------------------------------
extern "C" void kernel_launch(void* const* d_in, const int* in_sizes, int n_in,
                              void* d_out, int out_size, void* d_ws, size_t ws_size,
                              hipStream_t stream) {
  const float* features = (const float*)d_in[0];
  const float* slots    = (const float*)d_in[1];
  const float* tok_w    = (const float*)d_in[2];
  const float* tok_b    = (const float*)d_in[3];
  const float* slot_g   = (const float*)d_in[4];
  const float* slot_b   = (const float*)d_in[5];
  const float* ln1_g    = (const float*)d_in[6];
  const float* ln1_b    = (const float*)d_in[7];
  const float* ln2_g    = (const float*)d_in[8];
  const float* ln2_b    = (const float*)d_in[9];
  const float* ln3_g    = (const float*)d_in[10];
  const float* ln3_b    = (const float*)d_in[11];
  const float* sa_qw = (const float*)d_in[12]; const float* sa_qb = (const float*)d_in[13];
  const float* sa_kw = (const float*)d_in[14]; const float* sa_kb = (const float*)d_in[15];
  const float* sa_vw = (const float*)d_in[16]; const float* sa_vb = (const float*)d_in[17];
  const float* sa_ow = (const float*)d_in[18]; const float* sa_ob = (const float*)d_in[19];
  const float* ca_qw = (const float*)d_in[20]; const float* ca_qb = (const float*)d_in[21];
  const float* ca_kw = (const float*)d_in[22]; const float* ca_kb = (const float*)d_in[23];
  const float* ca_vw = (const float*)d_in[24]; const float* ca_vb = (const float*)d_in[25];
  const float* ca_ow = (const float*)d_in[26]; const float* ca_ob = (const float*)d_in[27];
  const float* ffn_w1 = (const float*)d_in[28]; const float* ffn_b1 = (const float*)d_in[29];
  const float* ffn_w2 = (const float*)d_in[30]; const float* ffn_b2 = (const float*)d_in[31];

  // workspace carve (256B aligned) — same layout as R1; qf/kf/vf reused as bf16
  char* wp = (char*)d_ws;
  size_t off = 0;
  auto carve = [&](size_t bytes) -> void* {
    void* p = wp + off;
    off = (off + bytes + 255) & ~(size_t)255;
    return p;
  };
  float*  tokens  = (float*)carve(8192ull * 512 * 4);
  ushort* hbf     = (ushort*)carve(8192ull * 512 * 2);
  float*  qf      = (float*)carve(8192ull * 512 * 4);
  float*  kf      = (float*)carve(8192ull * 512 * 4);
  float*  vf      = (float*)carve(8192ull * 512 * 4);
  ushort* cbf     = (ushort*)carve(8192ull * 512 * 2);
  ushort* hidbf   = (ushort*)carve(8192ull * 2048 * 2);  // also reused for features-bf16
  float*  slotsn  = (float*)carve(88ull * 512 * 4);
  float*  kc      = (float*)carve(88ull * 512 * 4);
  float*  vc      = (float*)carve(88ull * 512 * 4);
  float*  csum    = (float*)carve(8ull * 1024 * 11 * 4);
  ushort* tokwbf  = (ushort*)carve(512ull * 768 * 2);
  ushort* saqwbf  = (ushort*)carve(4ull * 512 * 512 * 2);
  ushort* sakwbf  = (ushort*)carve(4ull * 512 * 512 * 2);
  ushort* savwbf  = (ushort*)carve(4ull * 512 * 512 * 2);
  ushort* saowbf  = (ushort*)carve(4ull * 512 * 512 * 2);
  ushort* caqwbf  = (ushort*)carve(4ull * 512 * 512 * 2);
  ushort* caowbf  = (ushort*)carve(4ull * 512 * 512 * 2);
  ushort* w1bf    = (ushort*)carve(4ull * 2048 * 512 * 2);
  ushort* w2bf    = (ushort*)carve(4ull * 512 * 2048 * 2);
  ushort* featbf  = hidbf;  // alias: features-bf consumed before ffn hidden is produced
  ushort* qbf = (ushort*)qf;
  ushort* kbf = (ushort*)kf;
  ushort* vbf = (ushort*)vf;

  auto conv = [&](const float* s, ushort* d, int n) {
    const int n4 = n / 4;
    f32_to_bf16_vec<<<(n4 + 255) / 256, 256, 0, stream>>>(s, d, n4);
  };
  conv(features, featbf, 8192 * 768);
  conv(tok_w,  tokwbf, 512 * 768);
  conv(sa_qw,  saqwbf, 4 * 512 * 512);
  conv(sa_kw,  sakwbf, 4 * 512 * 512);
  conv(sa_vw,  savwbf, 4 * 512 * 512);
  conv(sa_ow,  saowbf, 4 * 512 * 512);
  conv(ca_qw,  caqwbf, 4 * 512 * 512);
  conv(ca_ow,  caowbf, 4 * 512 * 512);
  conv(ffn_w1, w1bf,   4 * 2048 * 512);
  conv(ffn_w2, w2bf,   4 * 512 * 2048);

  hipMemsetAsync(csum, 0, 8ull * 1024 * 11 * 4, stream);

  // token embedding: tokens = features @ tok_w^T + tok_b
  gemm_bt<0><<<dim3(4, 64), 256, 0, stream>>>(featbf, tokwbf, tok_b, tokens, (ushort*)nullptr, 8192, 512, 768);
  // slots_n = LN(slots)
  ln512<0><<<22, 256, 0, stream>>>(slots, slot_g, slot_b, slotsn, 88);

  for (int l = 0; l < 4; ++l) {
    const size_t wD = (size_t)l * 512 * 512;
    const size_t bD = (size_t)l * 512;
    // ---- self attention ----
    ln512<1><<<2048, 256, 0, stream>>>(tokens, ln1_g + bD, ln1_b + bD, hbf, 8192);
    gemm_bt<4><<<dim3(4, 64), 256, 0, stream>>>(hbf, saqwbf + wD, sa_qb + bD, (float*)nullptr, qbf, 8192, 512, 512);
    gemm_bt<4><<<dim3(4, 64), 256, 0, stream>>>(hbf, sakwbf + wD, sa_kb + bD, (float*)nullptr, kbf, 8192, 512, 512);
    gemm_bt<3><<<dim3(4, 64), 256, 0, stream>>>(hbf, savwbf + wD, sa_vb + bD, (float*)nullptr, vbf, 8192, 512, 512);
    attn_self_mfma<<<dim3(16, 64), 256, 0, stream>>>(qbf, kbf, vbf, cbf);
    gemm_bt<1><<<dim3(4, 64), 256, 0, stream>>>(cbf, saowbf + wD, sa_ob + bD, tokens, (ushort*)nullptr, 8192, 512, 512);
    // ---- cross attention ----
    ln512<1><<<2048, 256, 0, stream>>>(tokens, ln2_g + bD, ln2_b + bD, hbf, 8192);
    gemm_bt<4><<<dim3(4, 64), 256, 0, stream>>>(hbf, caqwbf + wD, ca_qb + bD, (float*)nullptr, qbf, 8192, 512, 512);
    gemm88<<<88, 256, 0, stream>>>(slotsn, ca_kw + wD, ca_kb + bD, kc);
    gemm88<<<88, 256, 0, stream>>>(slotsn, ca_vw + wD, ca_vb + bD, vc);
    l2norm64<<<176, 256, 0, stream>>>(kc, 704);
    attn_cross<<<dim3(8, 64), 128, 0, stream>>>(qbf, kc, vc, cbf, csum);
    gemm_bt<1><<<dim3(4, 64), 256, 0, stream>>>(cbf, caowbf + wD, ca_ob + bD, tokens, (ushort*)nullptr, 8192, 512, 512);
    // ---- FFN ----
    const size_t wM = (size_t)l * 2048 * 512;
    const size_t bM = (size_t)l * 2048;
    ln512<1><<<2048, 256, 0, stream>>>(tokens, ln3_g + bD, ln3_b + bD, hbf, 8192);
    gemm_bt<2><<<dim3(16, 64), 256, 0, stream>>>(hbf, w1bf + wM, ffn_b1 + bM, (float*)nullptr, hidbf, 8192, 2048, 512);
    gemm_bt<1><<<dim3(4, 64), 256, 0, stream>>>(hidbf, w2bf + wM, ffn_b2 + bD, tokens, (ushort*)nullptr, 8192, 512, 2048);
  }

  finalize<<<16736, 256, 0, stream>>>(tokens, csum, (float*)d_out);
}

// Round 3
// 1385.017 us; speedup vs baseline: 2.7833x; 1.3420x over previous
//
#include <hip/hip_runtime.h>
#include <math.h>

#define DEV __device__ __forceinline__

typedef __attribute__((ext_vector_type(4))) float f32x4;
typedef __attribute__((ext_vector_type(8))) short bf16x8;

DEV ushort f2bf(float x) {
  unsigned u = __float_as_uint(x);
  u = (u + 0x7FFFu + ((u >> 16) & 1u)) >> 16;
  return (ushort)u;
}

DEV float bf2f(ushort u) { return __uint_as_float(((unsigned)u) << 16); }

DEV float gelu_exact(float x) {
  return 0.5f * x * (1.0f + erff(x * 0.70710678118654752f));
}

DEV void async16(const void* g, void* l) {
  __builtin_amdgcn_global_load_lds((const __attribute__((address_space(1))) void*)g,
                                   (__attribute__((address_space(3))) void*)l, 16, 0, 0);
}

// ---------------------------------------------------------------------------
// f32 -> bf16 elementwise convert (n divisible by 4)
// ---------------------------------------------------------------------------
__global__ void f32_to_bf16_vec(const float* __restrict__ src, ushort* __restrict__ dst, int n4) {
  int i = blockIdx.x * 256 + threadIdx.x;
  if (i < n4) {
    float4 f = ((const float4*)src)[i];
    ushort4 u;
    u.x = f2bf(f.x); u.y = f2bf(f.y); u.z = f2bf(f.z); u.w = f2bf(f.w);
    ((ushort4*)dst)[i] = u;
  }
}

// ---------------------------------------------------------------------------
// Weight packing: qkv -> [3*512, 512] per layer (bf16); kv -> [2*512, 512]
// ---------------------------------------------------------------------------
__global__ void pack_qkv_w(const float* __restrict__ qw, const float* __restrict__ kw,
                           const float* __restrict__ vw, ushort* __restrict__ dst) {
  const int i = blockIdx.x * 256 + threadIdx.x;   // handles 4 elems
  if (i >= 786432) return;
  const int o = i * 4;
  const int layer = o / 786432;   // 3*512*512 per layer
  const int r = o % 786432;
  const int sel = r / 262144, off = r % 262144;
  const float* s = (sel == 0 ? qw : sel == 1 ? kw : vw) + (size_t)layer * 262144 + off;
  float4 f = *(const float4*)s;
  ushort4 u;
  u.x = f2bf(f.x); u.y = f2bf(f.y); u.z = f2bf(f.z); u.w = f2bf(f.w);
  ((ushort4*)dst)[i] = u;
}

__global__ void pack_kv_w(const float* __restrict__ kw, const float* __restrict__ vw,
                          ushort* __restrict__ dst) {
  const int i = blockIdx.x * 256 + threadIdx.x;
  if (i >= 524288) return;
  const int o = i * 4;
  const int layer = o / 524288;   // 2*512*512 per layer
  const int r = o % 524288;
  const int sel = r / 262144, off = r % 262144;
  const float* s = (sel == 0 ? kw : vw) + (size_t)layer * 262144 + off;
  float4 f = *(const float4*)s;
  ushort4 u;
  u.x = f2bf(f.x); u.y = f2bf(f.y); u.z = f2bf(f.z); u.w = f2bf(f.w);
  ((ushort4*)dst)[i] = u;
}

__global__ void pack_qkv_b(const float* __restrict__ qb, const float* __restrict__ kb,
                           const float* __restrict__ vb, float* __restrict__ dst) {
  const int i = blockIdx.x * 256 + threadIdx.x;
  if (i >= 6144) return;
  const int layer = i / 1536, r = i % 1536;
  const int sel = r / 512, off = r % 512;
  dst[i] = (sel == 0 ? qb : sel == 1 ? kb : vb)[layer * 512 + off];
}

__global__ void pack_kv_b(const float* __restrict__ kb, const float* __restrict__ vb,
                          float* __restrict__ dst) {
  const int i = blockIdx.x * 256 + threadIdx.x;
  if (i >= 4096) return;
  const int layer = i / 1024, r = i % 1024;
  const int sel = r / 512, off = r % 512;
  dst[i] = (sel == 0 ? kb : vb)[layer * 512 + off];
}

// ---------------------------------------------------------------------------
// 128x128-tile bf16 GEMM:  Y[M,N] = A[M,K] @ W[N,K]^T + bias
// EPI 0: Yf=val  1: Yf+=val  2: Ybf=bf16(gelu)  3: Ybf=bf16(val)
// EPI 4: per-head(64col) l2norm bf16   5: norm cols<512, plain rest (kv-slots)
// EPI 6: norm cols<1024, plain rest (qkv)
// ---------------------------------------------------------------------------
template <int EPI>
__launch_bounds__(256, 2)
__global__ void gemm_bt(const ushort* __restrict__ A, const ushort* __restrict__ W,
                        const float* __restrict__ bias, float* __restrict__ Yf,
                        ushort* __restrict__ Ybf, int M, int N, int K) {
  __shared__ ushort As[128 * 32];
  __shared__ ushort Bs[128 * 32];
  const int tid  = threadIdx.x;
  const int lane = tid & 63;
  const int wave = tid >> 6;
  const int wr = wave >> 1, wc = wave & 1;
  const int m0 = blockIdx.y * 128, n0 = blockIdx.x * 128;
  const int q = lane >> 4, ln = lane & 15;
  const int srow = lane >> 2;
  const int scol = (lane & 3) * 8;

  f32x4 acc[4][4] = {};

  const ushort* gA = A + (size_t)(m0 + wave * 32 + srow) * K + scol;
  const ushort* gB = W + (size_t)(n0 + wave * 32 + srow) * K + scol;
  ushort* lA = &As[(wave * 32) * 32];
  ushort* lB = &Bs[(wave * 32) * 32];

  for (int k0 = 0; k0 < K; k0 += 32) {
    async16(gA + k0, lA);
    async16(gA + k0 + (size_t)16 * K, lA + 16 * 32);
    async16(gB + k0, lB);
    async16(gB + k0 + (size_t)16 * K, lB + 16 * 32);
    __syncthreads();
    bf16x8 af[4], bfr[4];
#pragma unroll
    for (int t = 0; t < 4; ++t)
      af[t] = *(const bf16x8*)&As[(wr * 64 + t * 16 + ln) * 32 + q * 8];
#pragma unroll
    for (int t = 0; t < 4; ++t)
      bfr[t] = *(const bf16x8*)&Bs[(wc * 64 + t * 16 + ln) * 32 + q * 8];
#pragma unroll
    for (int mt = 0; mt < 4; ++mt)
#pragma unroll
      for (int nt = 0; nt < 4; ++nt)
        acc[mt][nt] = __builtin_amdgcn_mfma_f32_16x16x32_bf16(af[mt], bfr[nt], acc[mt][nt], 0, 0, 0);
    __syncthreads();
  }

  if (EPI >= 4) {
    const int chunk = (n0 + wc * 64) >> 9;
    const bool donorm = (EPI == 4) || (EPI == 5 && chunk == 0) || (EPI == 6 && chunk < 2);
#pragma unroll
    for (int mt = 0; mt < 4; ++mt) {
      const int gm = m0 + wr * 64 + mt * 16 + q * 4;
      float val[4][4];  // [nt][r]
#pragma unroll
      for (int nt = 0; nt < 4; ++nt) {
        const float bi = bias[n0 + wc * 64 + nt * 16 + ln];
#pragma unroll
        for (int r = 0; r < 4; ++r) val[nt][r] = acc[mt][nt][r] + bi;
      }
#pragma unroll
      for (int r = 0; r < 4; ++r) {
        float inv = 1.f;
        if (donorm) {
          float ss = val[0][r]*val[0][r] + val[1][r]*val[1][r] +
                     val[2][r]*val[2][r] + val[3][r]*val[3][r];
          ss += __shfl_xor(ss, 1);
          ss += __shfl_xor(ss, 2);
          ss += __shfl_xor(ss, 4);
          ss += __shfl_xor(ss, 8);
          inv = 1.f / fmaxf(sqrtf(ss), 1e-6f);
        }
#pragma unroll
        for (int nt = 0; nt < 4; ++nt) {
          const int gn = n0 + wc * 64 + nt * 16 + ln;
          Ybf[(size_t)(gm + r) * N + gn] = f2bf(val[nt][r] * inv);
        }
      }
    }
  } else {
#pragma unroll
    for (int mt = 0; mt < 4; ++mt) {
      const int gm = m0 + wr * 64 + mt * 16 + q * 4;
#pragma unroll
      for (int nt = 0; nt < 4; ++nt) {
        const int gn = n0 + wc * 64 + nt * 16 + ln;
        const float bi = bias[gn];
#pragma unroll
        for (int r = 0; r < 4; ++r) {
          const float val = acc[mt][nt][r] + bi;
          const size_t idx = (size_t)(gm + r) * N + gn;
          if (EPI == 0)      Yf[idx] = val;
          else if (EPI == 1) Yf[idx] += val;
          else if (EPI == 2) Ybf[idx] = f2bf(gelu_exact(val));
          else               Ybf[idx] = f2bf(val);
        }
      }
    }
  }
}

// ---------------------------------------------------------------------------
// 64x64-tile bf16 GEMM (4 blocks/CU for small-N shapes). Same EPI set (0,1,3,4).
// EPI4: per-head l2norm via cross-wave LDS reduction (head=64 cols = 2 waves).
// ---------------------------------------------------------------------------
template <int EPI>
__launch_bounds__(256, 4)
__global__ void gemm_bt64(const ushort* __restrict__ A, const ushort* __restrict__ W,
                          const float* __restrict__ bias, float* __restrict__ Yf,
                          ushort* __restrict__ Ybf, int M, int N, int K) {
  __shared__ ushort As[64 * 32];
  __shared__ ushort Bs[64 * 32];
  __shared__ float red[2][32][2];
  const int tid = threadIdx.x, lane = tid & 63, wave = tid >> 6;
  const int wr = wave >> 1, wc = wave & 1;
  const int m0 = blockIdx.y * 64, n0 = blockIdx.x * 64;
  const int q = lane >> 4, ln = lane & 15;

  f32x4 acc[2][2] = {};
  const ushort* gA = A + (size_t)(m0 + wave * 16 + (lane >> 2)) * K + (lane & 3) * 8;
  const ushort* gB = W + (size_t)(n0 + wave * 16 + (lane >> 2)) * K + (lane & 3) * 8;
  ushort* lA = &As[wave * 16 * 32];
  ushort* lB = &Bs[wave * 16 * 32];

  for (int k0 = 0; k0 < K; k0 += 32) {
    async16(gA + k0, lA);
    async16(gB + k0, lB);
    __syncthreads();
    bf16x8 af[2], bfr[2];
#pragma unroll
    for (int t = 0; t < 2; ++t)
      af[t] = *(const bf16x8*)&As[(wr * 32 + t * 16 + ln) * 32 + q * 8];
#pragma unroll
    for (int t = 0; t < 2; ++t)
      bfr[t] = *(const bf16x8*)&Bs[(wc * 32 + t * 16 + ln) * 32 + q * 8];
#pragma unroll
    for (int mt = 0; mt < 2; ++mt)
#pragma unroll
      for (int nt = 0; nt < 2; ++nt)
        acc[mt][nt] = __builtin_amdgcn_mfma_f32_16x16x32_bf16(af[mt], bfr[nt], acc[mt][nt], 0, 0, 0);
    __syncthreads();
  }

  if (EPI == 4) {
    float val[2][2][4];  // [mt][nt][r]
#pragma unroll
    for (int mt = 0; mt < 2; ++mt)
#pragma unroll
      for (int nt = 0; nt < 2; ++nt) {
        const float bi = bias[n0 + wc * 32 + nt * 16 + ln];
#pragma unroll
        for (int r = 0; r < 4; ++r) val[mt][nt][r] = acc[mt][nt][r] + bi;
      }
#pragma unroll
    for (int mt = 0; mt < 2; ++mt)
#pragma unroll
      for (int r = 0; r < 4; ++r) {
        float ss = val[mt][0][r]*val[mt][0][r] + val[mt][1][r]*val[mt][1][r];
        ss += __shfl_xor(ss, 1);
        ss += __shfl_xor(ss, 2);
        ss += __shfl_xor(ss, 4);
        ss += __shfl_xor(ss, 8);
        if (ln == 0) red[wr][mt * 16 + q * 4 + r][wc] = ss;
      }
    __syncthreads();
#pragma unroll
    for (int mt = 0; mt < 2; ++mt) {
      const int gm = m0 + wr * 32 + mt * 16 + q * 4;
#pragma unroll
      for (int r = 0; r < 4; ++r) {
        const float tot = red[wr][mt * 16 + q * 4 + r][0] + red[wr][mt * 16 + q * 4 + r][1];
        const float inv = 1.f / fmaxf(sqrtf(tot), 1e-6f);
#pragma unroll
        for (int nt = 0; nt < 2; ++nt) {
          const int gn = n0 + wc * 32 + nt * 16 + ln;
          Ybf[(size_t)(gm + r) * N + gn] = f2bf(val[mt][nt][r] * inv);
        }
      }
    }
  } else {
#pragma unroll
    for (int mt = 0; mt < 2; ++mt) {
      const int gm = m0 + wr * 32 + mt * 16 + q * 4;
#pragma unroll
      for (int nt = 0; nt < 2; ++nt) {
        const int gn = n0 + wc * 32 + nt * 16 + ln;
        const float bi = bias[gn];
#pragma unroll
        for (int r = 0; r < 4; ++r) {
          const float val = acc[mt][nt][r] + bi;
          const size_t idx = (size_t)(gm + r) * N + gn;
          if (EPI == 0)      Yf[idx] = val;
          else if (EPI == 1) Yf[idx] += val;
          else               Ybf[idx] = f2bf(val);
        }
      }
    }
  }
}

// ---------------------------------------------------------------------------
// LayerNorm over D=512, one wave per row. BF=1: bf16 out, BF=0: f32 out
// ---------------------------------------------------------------------------
template <int BF>
__launch_bounds__(256)
__global__ void ln512(const float* __restrict__ X, const float* __restrict__ G,
                      const float* __restrict__ Bb, void* __restrict__ Yv, int rows) {
  const int lane = threadIdx.x & 63;
  const int wave = threadIdx.x >> 6;
  const int row = blockIdx.x * 4 + wave;
  if (row >= rows) return;
  const float* x = X + (size_t)row * 512 + lane * 8;
  float4 v0 = *(const float4*)x;
  float4 v1 = *(const float4*)(x + 4);
  float s = v0.x + v0.y + v0.z + v0.w + v1.x + v1.y + v1.z + v1.w;
#pragma unroll
  for (int off = 32; off; off >>= 1) s += __shfl_xor(s, off);
  const float mean = s * (1.f / 512.f);
  float d[8] = {v0.x - mean, v0.y - mean, v0.z - mean, v0.w - mean,
                v1.x - mean, v1.y - mean, v1.z - mean, v1.w - mean};
  float ss = d[0]*d[0] + d[1]*d[1] + d[2]*d[2] + d[3]*d[3] +
             d[4]*d[4] + d[5]*d[5] + d[6]*d[6] + d[7]*d[7];
#pragma unroll
  for (int off = 32; off; off >>= 1) ss += __shfl_xor(ss, off);
  const float rstd = rsqrtf(ss * (1.f / 512.f) + 1e-5f);
  const float* gp = G + lane * 8;
  const float* bp = Bb + lane * 8;
  float4 g0 = *(const float4*)gp, g1 = *(const float4*)(gp + 4);
  float4 b0 = *(const float4*)bp, b1 = *(const float4*)(bp + 4);
  float y[8];
  y[0] = d[0]*rstd*g0.x + b0.x; y[1] = d[1]*rstd*g0.y + b0.y;
  y[2] = d[2]*rstd*g0.z + b0.z; y[3] = d[3]*rstd*g0.w + b0.w;
  y[4] = d[4]*rstd*g1.x + b1.x; y[5] = d[5]*rstd*g1.y + b1.y;
  y[6] = d[6]*rstd*g1.z + b1.z; y[7] = d[7]*rstd*g1.w + b1.w;
  if (BF) {
    ushort* o = (ushort*)Yv + (size_t)row * 512 + lane * 8;
    ushort4 u0, u1;
    u0.x = f2bf(y[0]); u0.y = f2bf(y[1]); u0.z = f2bf(y[2]); u0.w = f2bf(y[3]);
    u1.x = f2bf(y[4]); u1.y = f2bf(y[5]); u1.z = f2bf(y[6]); u1.w = f2bf(y[7]);
    *(ushort4*)o = u0; *(ushort4*)(o + 4) = u1;
  } else {
    float* o = (float*)Yv + (size_t)row * 512 + lane * 8;
    *(float4*)o = make_float4(y[0], y[1], y[2], y[3]);
    *(float4*)(o + 4) = make_float4(y[4], y[5], y[6], y[7]);
  }
}

// ---------------------------------------------------------------------------
// Causal self-attention, MFMA flash-style, 128-row Q tiles.
// QKV fused layout: row stride 1536, Q at +0, K at +512, V at +1024 (bf16).
// grid (8, 64), block 256 = 4 waves; wave owns 32 q-rows (2 m-frags).
// ---------------------------------------------------------------------------
__launch_bounds__(256, 2)
__global__ void attn_self_mfma(const ushort* __restrict__ QKV, ushort* __restrict__ O) {
  constexpr int LDK = 72;
  __shared__ ushort Ks[64 * LDK];
  __shared__ ushort Vt[64 * LDK];          // transposed: [d][k]
  __shared__ ushort Ps[4][32 * LDK];       // per-wave P scratch; doubles as Q staging
  ushort* Qstage = &Ps[0][0];              // [128][LDK]
  const int qt = blockIdx.x, bh = blockIdx.y;
  const int b = bh >> 3, h = bh & 7;
  const size_t base = (size_t)b * 1024 * 1536 + h * 64;
  const int tid = threadIdx.x, lane = tid & 63, wave = tid >> 6;
  const int quad = lane >> 4, ln = lane & 15;

  // stage Q tile (128 x 64) into Qstage
#pragma unroll
  for (int it = 0; it < 4; ++it) {
    const int idx = tid + 256 * it;
    const int r = idx >> 3, c = (idx & 7) * 8;
    *(uint4*)&Qstage[r * LDK + c] =
        *(const uint4*)(QKV + base + (size_t)(qt * 128 + r) * 1536 + c);
  }
  __syncthreads();
  bf16x8 qf[2][2];
#pragma unroll
  for (int mt = 0; mt < 2; ++mt)
#pragma unroll
    for (int kc = 0; kc < 2; ++kc)
      qf[mt][kc] = *(const bf16x8*)&Qstage[(wave * 32 + mt * 16 + ln) * LDK + kc * 32 + quad * 8];

  float m_r[2][4], l_r[2][4];
  f32x4 o_acc[2][4] = {};
#pragma unroll
  for (int mt = 0; mt < 2; ++mt)
#pragma unroll
    for (int r = 0; r < 4; ++r) { m_r[mt][r] = -1e30f; l_r[mt][r] = 0.f; }

  const int ktmax = 2 * qt + 1;
  for (int kt = 0; kt <= ktmax; ++kt) {
    __syncthreads();  // all waves done with previous tile's frags (and Q frags)
    {
      const int r = tid >> 2, c0 = (tid & 3) * 16;
      const ushort* ksrc = QKV + base + 512 + (size_t)(kt * 64 + r) * 1536 + c0;
      *(uint4*)&Ks[r * LDK + c0]     = *(const uint4*)ksrc;
      *(uint4*)&Ks[r * LDK + c0 + 8] = *(const uint4*)(ksrc + 8);
      // V transposed: pairs of k-rows packed as b32 writes
      const int kk = (tid & 31) * 2, d0 = (tid >> 5) * 8;
      const ushort* vs = QKV + base + 1024 + (size_t)(kt * 64 + kk) * 1536 + d0;
      uint4 va = *(const uint4*)vs;
      uint4 vb = *(const uint4*)(vs + 1536);
      const ushort* ua = (const ushort*)&va;
      const ushort* ub = (const ushort*)&vb;
#pragma unroll
      for (int j = 0; j < 8; ++j)
        *(unsigned*)&Vt[(d0 + j) * LDK + kk] = (unsigned)ua[j] | ((unsigned)ub[j] << 16);
    }
    __syncthreads();

    // S = Q K^T  (32q x 64k per wave)
    bf16x8 kf[4][2];
#pragma unroll
    for (int kb = 0; kb < 4; ++kb)
#pragma unroll
      for (int kc = 0; kc < 2; ++kc)
        kf[kb][kc] = *(const bf16x8*)&Ks[(kb * 16 + ln) * LDK + kc * 32 + quad * 8];
    f32x4 s[2][4] = {};
#pragma unroll
    for (int mt = 0; mt < 2; ++mt)
#pragma unroll
      for (int kb = 0; kb < 4; ++kb) {
        s[mt][kb] = __builtin_amdgcn_mfma_f32_16x16x32_bf16(qf[mt][0], kf[kb][0], s[mt][kb], 0, 0, 0);
        s[mt][kb] = __builtin_amdgcn_mfma_f32_16x16x32_bf16(qf[mt][1], kf[kb][1], s[mt][kb], 0, 0, 0);
      }
#pragma unroll
    for (int mt = 0; mt < 2; ++mt)
#pragma unroll
      for (int kb = 0; kb < 4; ++kb)
#pragma unroll
        for (int r = 0; r < 4; ++r) s[mt][kb][r] *= 0.125f;
    if (kt >= 2 * qt) {  // diagonal region
#pragma unroll
      for (int mt = 0; mt < 2; ++mt) {
        const int qrow0 = qt * 128 + wave * 32 + mt * 16 + quad * 4;
#pragma unroll
        for (int kb = 0; kb < 4; ++kb) {
          const int kcol = kt * 64 + kb * 16 + ln;
#pragma unroll
          for (int r = 0; r < 4; ++r)
            if (kcol > qrow0 + r) s[mt][kb][r] = -1e30f;
        }
      }
    }

    // online softmax per (mt, r)
#pragma unroll
    for (int mt = 0; mt < 2; ++mt) {
#pragma unroll
      for (int r = 0; r < 4; ++r) {
        float mx = fmaxf(fmaxf(s[mt][0][r], s[mt][1][r]), fmaxf(s[mt][2][r], s[mt][3][r]));
        mx = fmaxf(mx, __shfl_xor(mx, 1));
        mx = fmaxf(mx, __shfl_xor(mx, 2));
        mx = fmaxf(mx, __shfl_xor(mx, 4));
        mx = fmaxf(mx, __shfl_xor(mx, 8));
        const float mnew = fmaxf(m_r[mt][r], mx);
        const float alpha = __expf(m_r[mt][r] - mnew);
        m_r[mt][r] = mnew;
        float sum = 0.f;
#pragma unroll
        for (int kb = 0; kb < 4; ++kb) {
          const float p = __expf(s[mt][kb][r] - mnew);
          sum += p;
          Ps[wave][(mt * 16 + quad * 4 + r) * LDK + kb * 16 + ln] = f2bf(p);
        }
        sum += __shfl_xor(sum, 1);
        sum += __shfl_xor(sum, 2);
        sum += __shfl_xor(sum, 4);
        sum += __shfl_xor(sum, 8);
        l_r[mt][r] = l_r[mt][r] * alpha + sum;
#pragma unroll
        for (int db = 0; db < 4; ++db) o_acc[mt][db][r] *= alpha;
      }
    }
    __builtin_amdgcn_wave_barrier();  // P write -> read ordering (intra-wave)

    // O += P V
    bf16x8 pf[2][2];
#pragma unroll
    for (int mt = 0; mt < 2; ++mt)
#pragma unroll
      for (int kc = 0; kc < 2; ++kc)
        pf[mt][kc] = *(const bf16x8*)&Ps[wave][(mt * 16 + ln) * LDK + kc * 32 + quad * 8];
#pragma unroll
    for (int db = 0; db < 4; ++db) {
      bf16x8 vf0 = *(const bf16x8*)&Vt[(db * 16 + ln) * LDK + quad * 8];
      bf16x8 vf1 = *(const bf16x8*)&Vt[(db * 16 + ln) * LDK + 32 + quad * 8];
#pragma unroll
      for (int mt = 0; mt < 2; ++mt) {
        o_acc[mt][db] = __builtin_amdgcn_mfma_f32_16x16x32_bf16(pf[mt][0], vf0, o_acc[mt][db], 0, 0, 0);
        o_acc[mt][db] = __builtin_amdgcn_mfma_f32_16x16x32_bf16(pf[mt][1], vf1, o_acc[mt][db], 0, 0, 0);
      }
    }
  }

  // epilogue: O / l -> bf16 (output stride 512)
  const size_t obase = (size_t)b * 1024 * 512 + h * 64;
#pragma unroll
  for (int mt = 0; mt < 2; ++mt) {
    const int qrow0 = qt * 128 + wave * 32 + mt * 16 + quad * 4;
#pragma unroll
    for (int r = 0; r < 4; ++r) {
      const float inv = 1.f / l_r[mt][r];
      ushort* dst = O + obase + (size_t)(qrow0 + r) * 512;
#pragma unroll
      for (int db = 0; db < 4; ++db)
        dst[db * 16 + ln] = f2bf(o_acc[mt][db][r] * inv);
    }
  }
}

// ---------------------------------------------------------------------------
// Cross-attention over 11 slots + cross_sum accumulation (head-mean, x1/8).
// Q bf16 (l2-normalized, stride 512); KV bf16 packed [88][1024] (k|v).
// grid (8 tiles of 128, 64 b*h), block 128.
// ---------------------------------------------------------------------------
__launch_bounds__(128)
__global__ void attn_cross(const ushort* __restrict__ Q, const ushort* __restrict__ KV,
                           ushort* __restrict__ Obf, float* __restrict__ csum) {
  const int rt = blockIdx.x;
  const int bh = blockIdx.y;
  const int b = bh >> 3, h = bh & 7;
  const int tid = threadIdx.x;
  __shared__ float Qs[128][65];
  __shared__ float Kcs[11][64];
  __shared__ float Vcs[11][64];
  const size_t base = ((size_t)(b * 1024)) * 512 + h * 64;

  for (int i = tid; i < 704; i += 128) {
    const int k = i >> 6, d = i & 63;
    Kcs[k][d] = bf2f(KV[((size_t)(b * 11 + k)) * 1024 + h * 64 + d]);
    Vcs[k][d] = bf2f(KV[((size_t)(b * 11 + k)) * 1024 + 512 + h * 64 + d]);
  }
#pragma unroll
  for (int it = 0; it < 8; ++it) {
    const int idx = tid + 128 * it;
    const int r = idx >> 3, c = (idx & 7) * 8;
    uint4 t = *(const uint4*)(Q + base + (size_t)(rt * 128 + r) * 512 + c);
    const ushort* u = (const ushort*)&t;
#pragma unroll
    for (int j = 0; j < 8; ++j) Qs[r][c + j] = bf2f(u[j]);
  }
  __syncthreads();

  float s[11] = {};
  for (int d = 0; d < 64; ++d) {
    const float qv = Qs[tid][d];
#pragma unroll
    for (int k = 0; k < 11; ++k) s[k] += qv * Kcs[k][d];
  }
  float m = s[0] * 0.125f;
#pragma unroll
  for (int k = 0; k < 11; ++k) { s[k] *= 0.125f; m = fmaxf(m, s[k]); }
  float l = 0.f;
#pragma unroll
  for (int k = 0; k < 11; ++k) { s[k] = __expf(s[k] - m); l += s[k]; }
  const float inv = 1.f / l;
#pragma unroll
  for (int k = 0; k < 11; ++k) s[k] *= inv;

  const int qrow = rt * 128 + tid;
  float* cs = csum + ((size_t)(b * 1024 + qrow)) * 11;
#pragma unroll
  for (int k = 0; k < 11; ++k) atomicAdd(cs + k, s[k] * 0.125f);

  ushort* dst = Obf + base + (size_t)qrow * 512;
#pragma unroll
  for (int d0 = 0; d0 < 64; d0 += 8) {
    ushort o8[8];
#pragma unroll
    for (int j = 0; j < 8; ++j) {
      float acc = 0.f;
#pragma unroll
      for (int k = 0; k < 11; ++k) acc += s[k] * Vcs[k][d0 + j];
      o8[j] = f2bf(acc);
    }
    *(uint4*)(dst + d0) = *(const uint4*)o8;
  }
}

// ---------------------------------------------------------------------------
// Final output: d_out = [tokens (8*1024*512 f32), masks = csum/4 (8*1024*11)]
// ---------------------------------------------------------------------------
__global__ void finalize(const float* __restrict__ tokens, const float* __restrict__ csum,
                         float* __restrict__ out) {
  const int i = blockIdx.x * 256 + threadIdx.x;
  if (i < 4194304) out[i] = tokens[i];
  else if (i < 4284416) out[i] = csum[i - 4194304] * 0.25f;
}

// ---------------------------------------------------------------------------
// Host
// ---------------------------------------------------------------------------
extern "C" void kernel_launch(void* const* d_in, const int* in_sizes, int n_in,
                              void* d_out, int out_size, void* d_ws, size_t ws_size,
                              hipStream_t stream) {
  const float* features = (const float*)d_in[0];
  const float* slots    = (const float*)d_in[1];
  const float* tok_w    = (const float*)d_in[2];
  const float* tok_b    = (const float*)d_in[3];
  const float* slot_g   = (const float*)d_in[4];
  const float* slot_b   = (const float*)d_in[5];
  const float* ln1_g    = (const float*)d_in[6];
  const float* ln1_b    = (const float*)d_in[7];
  const float* ln2_g    = (const float*)d_in[8];
  const float* ln2_b    = (const float*)d_in[9];
  const float* ln3_g    = (const float*)d_in[10];
  const float* ln3_b    = (const float*)d_in[11];
  const float* sa_qw = (const float*)d_in[12]; const float* sa_qb = (const float*)d_in[13];
  const float* sa_kw = (const float*)d_in[14]; const float* sa_kb = (const float*)d_in[15];
  const float* sa_vw = (const float*)d_in[16]; const float* sa_vb = (const float*)d_in[17];
  const float* sa_ow = (const float*)d_in[18]; const float* sa_ob = (const float*)d_in[19];
  const float* ca_qw = (const float*)d_in[20]; const float* ca_qb = (const float*)d_in[21];
  const float* ca_kw = (const float*)d_in[22]; const float* ca_kb = (const float*)d_in[23];
  const float* ca_vw = (const float*)d_in[24]; const float* ca_vb = (const float*)d_in[25];
  const float* ca_ow = (const float*)d_in[26]; const float* ca_ob = (const float*)d_in[27];
  const float* ffn_w1 = (const float*)d_in[28]; const float* ffn_b1 = (const float*)d_in[29];
  const float* ffn_w2 = (const float*)d_in[30]; const float* ffn_b2 = (const float*)d_in[31];

  char* wp = (char*)d_ws;
  size_t off = 0;
  auto carve = [&](size_t bytes) -> void* {
    void* p = wp + off;
    off = (off + bytes + 255) & ~(size_t)255;
    return p;
  };
  float*  tokens  = (float*)carve(8192ull * 512 * 4);
  ushort* hbf     = (ushort*)carve(8192ull * 512 * 2);
  ushort* qkvbf   = (ushort*)carve(8192ull * 1536 * 2);
  ushort* qbf     = (ushort*)carve(8192ull * 512 * 2);
  ushort* cbf     = (ushort*)carve(8192ull * 512 * 2);
  ushort* hidbf   = (ushort*)carve(8192ull * 2048 * 2);  // also features-bf16 alias
  ushort* slotsn  = (ushort*)carve(128ull * 512 * 2);    // rows 88..127 pad (poison ok)
  ushort* kvc     = (ushort*)carve(128ull * 1024 * 2);
  float*  csum    = (float*)carve(8ull * 1024 * 11 * 4);
  ushort* tokwbf  = (ushort*)carve(512ull * 768 * 2);
  ushort* saowbf  = (ushort*)carve(4ull * 512 * 512 * 2);
  ushort* caqwbf  = (ushort*)carve(4ull * 512 * 512 * 2);
  ushort* caowbf  = (ushort*)carve(4ull * 512 * 512 * 2);
  ushort* w1bf    = (ushort*)carve(4ull * 2048 * 512 * 2);
  ushort* w2bf    = (ushort*)carve(4ull * 512 * 2048 * 2);
  ushort* qkvwbf  = (ushort*)carve(4ull * 1536 * 512 * 2);
  ushort* kvwbf   = (ushort*)carve(4ull * 1024 * 512 * 2);
  float*  qkvb    = (float*)carve(4ull * 1536 * 4);
  float*  kvb     = (float*)carve(4ull * 1024 * 4);
  ushort* featbf  = hidbf;

  auto conv = [&](const float* s, ushort* d, int n) {
    const int n4 = n / 4;
    f32_to_bf16_vec<<<(n4 + 255) / 256, 256, 0, stream>>>(s, d, n4);
  };
  conv(features, featbf, 8192 * 768);
  conv(tok_w,  tokwbf, 512 * 768);
  conv(sa_ow,  saowbf, 4 * 512 * 512);
  conv(ca_qw,  caqwbf, 4 * 512 * 512);
  conv(ca_ow,  caowbf, 4 * 512 * 512);
  conv(ffn_w1, w1bf,   4 * 2048 * 512);
  conv(ffn_w2, w2bf,   4 * 512 * 2048);
  pack_qkv_w<<<3072, 256, 0, stream>>>(sa_qw, sa_kw, sa_vw, qkvwbf);
  pack_kv_w<<<2048, 256, 0, stream>>>(ca_kw, ca_vw, kvwbf);
  pack_qkv_b<<<24, 256, 0, stream>>>(sa_qb, sa_kb, sa_vb, qkvb);
  pack_kv_b<<<16, 256, 0, stream>>>(ca_kb, ca_vb, kvb);

  hipMemsetAsync(csum, 0, 8ull * 1024 * 11 * 4, stream);

  // token embedding: tokens = features @ tok_w^T + tok_b  (64x64 tiles, 4 blk/CU)
  gemm_bt64<0><<<dim3(8, 128), 256, 0, stream>>>(featbf, tokwbf, tok_b, tokens, (ushort*)nullptr, 8192, 512, 768);
  // slots_n = LN(slots), bf16
  ln512<1><<<22, 256, 0, stream>>>(slots, slot_g, slot_b, slotsn, 88);

  for (int l = 0; l < 4; ++l) {
    const size_t wD = (size_t)l * 512 * 512;
    const size_t bD = (size_t)l * 512;
    // ---- self attention ----
    ln512<1><<<2048, 256, 0, stream>>>(tokens, ln1_g + bD, ln1_b + bD, hbf, 8192);
    gemm_bt<6><<<dim3(12, 64), 256, 0, stream>>>(hbf, qkvwbf + (size_t)l * 1536 * 512, qkvb + l * 1536,
                                                 (float*)nullptr, qkvbf, 8192, 1536, 512);
    attn_self_mfma<<<dim3(8, 64), 256, 0, stream>>>(qkvbf, cbf);
    gemm_bt64<1><<<dim3(8, 128), 256, 0, stream>>>(cbf, saowbf + wD, sa_ob + bD, tokens, (ushort*)nullptr, 8192, 512, 512);
    // ---- cross attention ----
    ln512<1><<<2048, 256, 0, stream>>>(tokens, ln2_g + bD, ln2_b + bD, hbf, 8192);
    gemm_bt64<4><<<dim3(8, 128), 256, 0, stream>>>(hbf, caqwbf + wD, ca_qb + bD, (float*)nullptr, qbf, 8192, 512, 512);
    gemm_bt<5><<<dim3(8, 1), 256, 0, stream>>>(slotsn, kvwbf + (size_t)l * 1024 * 512, kvb + l * 1024,
                                               (float*)nullptr, kvc, 128, 1024, 512);
    attn_cross<<<dim3(8, 64), 128, 0, stream>>>(qbf, kvc, cbf, csum);
    gemm_bt64<1><<<dim3(8, 128), 256, 0, stream>>>(cbf, caowbf + wD, ca_ob + bD, tokens, (ushort*)nullptr, 8192, 512, 512);
    // ---- FFN ----
    const size_t wM = (size_t)l * 2048 * 512;
    const size_t bM = (size_t)l * 2048;
    ln512<1><<<2048, 256, 0, stream>>>(tokens, ln3_g + bD, ln3_b + bD, hbf, 8192);
    gemm_bt<2><<<dim3(16, 64), 256, 0, stream>>>(hbf, w1bf + wM, ffn_b1 + bM, (float*)nullptr, hidbf, 8192, 2048, 512);
    gemm_bt64<1><<<dim3(8, 128), 256, 0, stream>>>(hidbf, w2bf + wM, ffn_b2 + bD, tokens, (ushort*)nullptr, 8192, 512, 2048);
  }

  finalize<<<16736, 256, 0, stream>>>(tokens, csum, (float*)d_out);
}